// Round 1
// baseline (35193.176 us; speedup 1.0000x reference)
//
#include <hip/hip_runtime.h>
#include <hip/hip_cooperative_groups.h>

namespace cg = cooperative_groups;

#define Tn  512
#define Bn  128
#define INn 64
#define Hn  1024

typedef __attribute__((ext_vector_type(8))) short bf16x8;
typedef __attribute__((ext_vector_type(4))) float f32x4;
typedef unsigned short u16;

__device__ __forceinline__ u16 f2bf(float f) {
  unsigned u = __float_as_uint(f);
  unsigned r = (u + 0x7fffu + ((u >> 16) & 1u)) >> 16;
  return (u16)r;
}
__device__ __forceinline__ float bf2f(u16 h) {
  return __uint_as_float(((unsigned)h) << 16);
}
__device__ __forceinline__ float sigmoidf_(float x) {
  return 1.0f / (1.0f + __expf(-x));
}
__device__ __forceinline__ float tanhf_(float x) {
  float e = __expf(-2.0f * fabsf(x));
  float t = (1.0f - e) / (1.0f + e);
  return copysignf(t, x);
}
__device__ __forceinline__ f32x4 mfma16(bf16x8 a, bf16x8 b, f32x4 c) {
  return __builtin_amdgcn_mfma_f32_16x16x32_bf16(a, b, c, 0, 0, 0);
}

// 3-gate GEMM, K=1024, A given as hi/lo bf16 split (fp32-effective A).
// Pointers are pre-offset by this lane's row*stride + lq*8.
__device__ __forceinline__ void gemm3(f32x4 acc[3],
                                      const u16* __restrict__ a_hi,
                                      const u16* __restrict__ a_lo,
                                      const u16* __restrict__ w0,
                                      const u16* __restrict__ w1,
                                      const u16* __restrict__ w2) {
#pragma unroll 4
  for (int kt = 0; kt < 32; ++kt) {
    const int k = kt * 32;
    bf16x8 ah = *(const bf16x8*)(a_hi + k);
    bf16x8 al = *(const bf16x8*)(a_lo + k);
    bf16x8 b0 = *(const bf16x8*)(w0 + k);
    bf16x8 b1 = *(const bf16x8*)(w1 + k);
    bf16x8 b2 = *(const bf16x8*)(w2 + k);
    acc[0] = mfma16(ah, b0, acc[0]);
    acc[1] = mfma16(ah, b1, acc[1]);
    acc[2] = mfma16(ah, b2, acc[2]);
    acc[0] = mfma16(al, b0, acc[0]);
    acc[1] = mfma16(al, b1, acc[1]);
    acc[2] = mfma16(al, b2, acc[2]);
  }
}

__global__ void cvt_bf16(const float* __restrict__ s, u16* __restrict__ d, int n) {
  int i = blockIdx.x * blockDim.x + threadIdx.x;
  if (i < n) d[i] = f2bf(s[i]);
}
__global__ void zero16(uint4* __restrict__ p, int n4) {
  int i = blockIdx.x * blockDim.x + threadIdx.x;
  if (i < n4) p[i] = make_uint4(0u, 0u, 0u, 0u);
}

// blocks 0..127: layer0 (+ linear on hsl==0); blocks 128..255: layer1.
// hA = layer0 hidden state (= layer1 input), hB = layer1 hidden state.
// Layout: h[parity][part(hi/lo)][B][H] bf16. State for step s at parity s&1.
__global__ __launch_bounds__(256, 1) void gru_main(
    const float* __restrict__ x,
    const float* __restrict__ b_ih0, const float* __restrict__ b_hh0,
    const float* __restrict__ b_ih1, const float* __restrict__ b_hh1,
    const float* __restrict__ b_lin,
    const u16* __restrict__ wih0, const u16* __restrict__ whh0,
    const u16* __restrict__ wih1, const u16* __restrict__ whh1,
    const u16* __restrict__ wlin,
    u16* __restrict__ hA, u16* __restrict__ hB,
    float* __restrict__ out) {
  cg::grid_group grid = cg::this_grid();
  const int blk  = blockIdx.x;
  const int tid  = threadIdx.x;
  const int wave = tid >> 6;
  const int lane = tid & 63;
  const int ln   = lane & 15;   // A-row / B-row / C-col within 16-tile
  const int lq   = lane >> 4;   // quad
  const int lq8  = lq * 8;
  const int layer = blk >> 7;
  const int lb   = blk & 127;
  const int bg   = lb >> 5;     // batch group 0..3
  const int hsl  = lb & 31;     // hidden slice 0..31
  const int m0   = bg * 32;
  const int h0   = hsl * 32;
  const int mi   = wave & 1;    // 16-row m-tile within 32
  const int q    = wave >> 1;   // 16-col group within 32
  const int arow = m0 + mi * 16 + ln;  // this lane's A (batch) row
  const int col  = h0 + q * 16 + ln;   // this lane's hidden column
  const size_t HB = (size_t)Bn * Hn;   // one [B][H] plane
  const f32x4 vzero = {0.f, 0.f, 0.f, 0.f};

  if (layer == 0) {
    const float bir = b_ih0[col],        biz = b_ih0[Hn + col],  bin_ = b_ih0[2 * Hn + col];
    const float bhr = b_hh0[col],        bhz = b_hh0[Hn + col],  bhn  = b_hh0[2 * Hn + col];
    const u16* w0  = whh0 + (size_t)col * Hn + lq8;
    const u16* w1  = whh0 + (size_t)(Hn + col) * Hn + lq8;
    const u16* w2  = whh0 + (size_t)(2 * Hn + col) * Hn + lq8;
    const u16* wi0 = wih0 + (size_t)col * INn + lq8;
    const u16* wi1 = wih0 + (size_t)(Hn + col) * INn + lq8;
    const u16* wi2 = wih0 + (size_t)(2 * Hn + col) * INn + lq8;

    const bool do_lin = (hsl == 0);
    const int lcol = q * 32 + ln;  // linear out cols: lcol and lcol+16
    float bl0 = 0.f, bl1 = 0.f;
    const u16 *L0 = wlin, *L1 = wlin;
    if (do_lin) {
      bl0 = b_lin[lcol];
      bl1 = b_lin[lcol + 16];
      L0 = wlin + (size_t)lcol * Hn + lq8;
      L1 = wlin + (size_t)(lcol + 16) * Hn + lq8;
    }

    for (int t = 0; t <= Tn + 1; ++t) {
      if (t < Tn) {
        const int rp = (t + 1) & 1;  // parity of h_{t-1}
        const int wp = t & 1;        // parity of h_t
        f32x4 accI[3] = {vzero, vzero, vzero};
        f32x4 accH[3] = {vzero, vzero, vzero};
        // gi = x_t @ w_ih0^T  (K=64, single-bf16 x)
        const float* xr = x + ((size_t)t * Bn + arow) * INn + lq8;
#pragma unroll
        for (int kt = 0; kt < 2; ++kt) {
          float4 xv0 = *(const float4*)(xr + kt * 32);
          float4 xv1 = *(const float4*)(xr + kt * 32 + 4);
          bf16x8 a;
          u16* ap = (u16*)&a;
          ap[0] = f2bf(xv0.x); ap[1] = f2bf(xv0.y); ap[2] = f2bf(xv0.z); ap[3] = f2bf(xv0.w);
          ap[4] = f2bf(xv1.x); ap[5] = f2bf(xv1.y); ap[6] = f2bf(xv1.z); ap[7] = f2bf(xv1.w);
          bf16x8 c0 = *(const bf16x8*)(wi0 + kt * 32);
          bf16x8 c1 = *(const bf16x8*)(wi1 + kt * 32);
          bf16x8 c2 = *(const bf16x8*)(wi2 + kt * 32);
          accI[0] = mfma16(a, c0, accI[0]);
          accI[1] = mfma16(a, c1, accI[1]);
          accI[2] = mfma16(a, c2, accI[2]);
        }
        // gh = h_{t-1} @ w_hh0^T  (K=1024, hi/lo)
        const u16* ahi = hA + (size_t)(rp * 2 + 0) * HB + (size_t)arow * Hn + lq8;
        const u16* alo = hA + (size_t)(rp * 2 + 1) * HB + (size_t)arow * Hn + lq8;
        gemm3(accH, ahi, alo, w0, w1, w2);
        // gates + state update
        u16* whiP = hA + (size_t)(wp * 2 + 0) * HB;
        u16* wloP = hA + (size_t)(wp * 2 + 1) * HB;
        const u16* rhiP = hA + (size_t)(rp * 2 + 0) * HB;
        const u16* rloP = hA + (size_t)(rp * 2 + 1) * HB;
#pragma unroll
        for (int i = 0; i < 4; ++i) {
          const int brow = m0 + mi * 16 + lq * 4 + i;
          const size_t idx = (size_t)brow * Hn + col;
          float r  = sigmoidf_(accI[0][i] + bir + accH[0][i] + bhr);
          float z  = sigmoidf_(accI[1][i] + biz + accH[1][i] + bhz);
          float nn = tanhf_(accI[2][i] + bin_ + r * (accH[2][i] + bhn));
          float hp = bf2f(rhiP[idx]) + bf2f(rloP[idx]);
          float hv = (1.0f - z) * nn + z * hp;
          u16 hh = f2bf(hv);
          whiP[idx] = hh;
          wloP[idx] = f2bf(hv - bf2f(hh));
        }
      }
      if (do_lin && t >= 2) {
        const int s2 = t - 2;
        const int p2 = s2 & 1;
        const u16* ahi = hB + (size_t)(p2 * 2 + 0) * HB + (size_t)arow * Hn + lq8;
        const u16* alo = hB + (size_t)(p2 * 2 + 1) * HB + (size_t)arow * Hn + lq8;
        f32x4 ac0 = vzero, ac1 = vzero;
#pragma unroll 4
        for (int kt = 0; kt < 32; ++kt) {
          const int k = kt * 32;
          bf16x8 ah = *(const bf16x8*)(ahi + k);
          bf16x8 al = *(const bf16x8*)(alo + k);
          bf16x8 c0 = *(const bf16x8*)(L0 + k);
          bf16x8 c1 = *(const bf16x8*)(L1 + k);
          ac0 = mfma16(ah, c0, ac0);
          ac1 = mfma16(ah, c1, ac1);
          ac0 = mfma16(al, c0, ac0);
          ac1 = mfma16(al, c1, ac1);
        }
#pragma unroll
        for (int i = 0; i < 4; ++i) {
          const int brow = m0 + mi * 16 + lq * 4 + i;
          float* orow = out + ((size_t)s2 * Bn + brow) * 64;
          orow[lcol]      = ac0[i] + bl0;
          orow[lcol + 16] = ac1[i] + bl1;
        }
      }
      grid.sync();
    }
  } else {
    // ----- layer 1 (step s = t-1) -----
    const float bir = b_ih1[col],        biz = b_ih1[Hn + col],  bin_ = b_ih1[2 * Hn + col];
    const float bhr = b_hh1[col],        bhz = b_hh1[Hn + col],  bhn  = b_hh1[2 * Hn + col];
    const u16* wi0 = wih1 + (size_t)col * Hn + lq8;
    const u16* wi1 = wih1 + (size_t)(Hn + col) * Hn + lq8;
    const u16* wi2 = wih1 + (size_t)(2 * Hn + col) * Hn + lq8;
    const u16* w0  = whh1 + (size_t)col * Hn + lq8;
    const u16* w1  = whh1 + (size_t)(Hn + col) * Hn + lq8;
    const u16* w2  = whh1 + (size_t)(2 * Hn + col) * Hn + lq8;

    for (int t = 0; t <= Tn + 1; ++t) {
      if (t >= 1 && t <= Tn) {
        const int s  = t - 1;
        const int sp = s & 1;        // parity of h1_s (input, written by layer0 at iter s)
        const int rp = (s + 1) & 1;  // parity of h2_{s-1}
        const int wp = s & 1;        // parity of h2_s
        f32x4 accI[3] = {vzero, vzero, vzero};
        f32x4 accH[3] = {vzero, vzero, vzero};
        // gi = h1_s @ w_ih1^T (K=1024, hi/lo)
        const u16* gihi = hA + (size_t)(sp * 2 + 0) * HB + (size_t)arow * Hn + lq8;
        const u16* gilo = hA + (size_t)(sp * 2 + 1) * HB + (size_t)arow * Hn + lq8;
        gemm3(accI, gihi, gilo, wi0, wi1, wi2);
        // gh = h2_{s-1} @ w_hh1^T
        const u16* ahi = hB + (size_t)(rp * 2 + 0) * HB + (size_t)arow * Hn + lq8;
        const u16* alo = hB + (size_t)(rp * 2 + 1) * HB + (size_t)arow * Hn + lq8;
        gemm3(accH, ahi, alo, w0, w1, w2);
        u16* whiP = hB + (size_t)(wp * 2 + 0) * HB;
        u16* wloP = hB + (size_t)(wp * 2 + 1) * HB;
        const u16* rhiP = hB + (size_t)(rp * 2 + 0) * HB;
        const u16* rloP = hB + (size_t)(rp * 2 + 1) * HB;
#pragma unroll
        for (int i = 0; i < 4; ++i) {
          const int brow = m0 + mi * 16 + lq * 4 + i;
          const size_t idx = (size_t)brow * Hn + col;
          float r  = sigmoidf_(accI[0][i] + bir + accH[0][i] + bhr);
          float z  = sigmoidf_(accI[1][i] + biz + accH[1][i] + bhz);
          float nn = tanhf_(accI[2][i] + bin_ + r * (accH[2][i] + bhn));
          float hp = bf2f(rhiP[idx]) + bf2f(rloP[idx]);
          float hv = (1.0f - z) * nn + z * hp;
          u16 hh = f2bf(hv);
          whiP[idx] = hh;
          wloP[idx] = f2bf(hv - bf2f(hh));
        }
      }
      grid.sync();
    }
  }
}

extern "C" void kernel_launch(void* const* d_in, const int* in_sizes, int n_in,
                              void* d_out, int out_size, void* d_ws, size_t ws_size,
                              hipStream_t stream) {
  (void)in_sizes; (void)n_in; (void)out_size; (void)ws_size;
  const float* x     = (const float*)d_in[0];
  const float* wih0f = (const float*)d_in[1];
  const float* whh0f = (const float*)d_in[2];
  const float* bih0  = (const float*)d_in[3];
  const float* bhh0  = (const float*)d_in[4];
  const float* wih1f = (const float*)d_in[5];
  const float* whh1f = (const float*)d_in[6];
  const float* bih1  = (const float*)d_in[7];
  const float* bhh1  = (const float*)d_in[8];
  const float* wlinf = (const float*)d_in[9];
  const float* blin  = (const float*)d_in[10];
  float* out = (float*)d_out;

  char* w = (char*)d_ws;
  u16* whh0 = (u16*)w; w += (size_t)3072 * 1024 * 2;
  u16* wih1 = (u16*)w; w += (size_t)3072 * 1024 * 2;
  u16* whh1 = (u16*)w; w += (size_t)3072 * 1024 * 2;
  u16* wih0 = (u16*)w; w += (size_t)3072 * 64 * 2;
  u16* wlin = (u16*)w; w += (size_t)64 * 1024 * 2;
  u16* hA   = (u16*)w; w += (size_t)2 * 2 * 128 * 1024 * 2;
  u16* hB   = (u16*)w; w += (size_t)2 * 2 * 128 * 1024 * 2;
  // total ws use: ~21.5 MB

  const int thr = 256;
  cvt_bf16<<<(3072 * 1024 + thr - 1) / thr, thr, 0, stream>>>(whh0f, whh0, 3072 * 1024);
  cvt_bf16<<<(3072 * 1024 + thr - 1) / thr, thr, 0, stream>>>(wih1f, wih1, 3072 * 1024);
  cvt_bf16<<<(3072 * 1024 + thr - 1) / thr, thr, 0, stream>>>(whh1f, whh1, 3072 * 1024);
  cvt_bf16<<<(3072 * 64 + thr - 1) / thr, thr, 0, stream>>>(wih0f, wih0, 3072 * 64);
  cvt_bf16<<<(64 * 1024 + thr - 1) / thr, thr, 0, stream>>>(wlinf, wlin, 64 * 1024);
  // zero hA+hB (contiguous, 2 MiB total)
  const int n4 = (int)((size_t)2 * 2 * 2 * 128 * 1024 * 2 / 16);
  zero16<<<(n4 + thr - 1) / thr, thr, 0, stream>>>((uint4*)hA, n4);

  void* args[] = {(void*)&x,    (void*)&bih0, (void*)&bhh0, (void*)&bih1, (void*)&bhh1,
                  (void*)&blin, (void*)&wih0, (void*)&whh0, (void*)&wih1, (void*)&whh1,
                  (void*)&wlin, (void*)&hA,   (void*)&hB,   (void*)&out};
  hipLaunchCooperativeKernel((const void*)gru_main, dim3(256), dim3(256), args, 0, stream);
}